// Round 9
// baseline (806.921 us; speedup 1.0000x reference)
//
#include <hip/hip_runtime.h>
#include <hip/hip_fp16.h>

#define N_NODES 65536
#define N_EDGES 2097152
#define NB      1024
#define FXD     78
#define DIM     32
#define EMBD    128
#define OUTD    128
#define VOCAB   26
#define PLEN    1000
#define KS      8
#define CLEN    121      // EMBD-KS+1
#define NF      32
#define FCX     (NF*CLEN)  // 3872
#define NBKT    256
#define EPB     8192     // edges per bucketA block (N_EDGES/256)
#define NSLICE  256      // stats partial slices
#define EROW    135      // skewed emb row stride: f(t)=t+(t>>4), max f(127)=134
#define UNIF    3518     // union region floats: max(sort scratch 1079 ints, embS 26*135+8)

// ---------------- bucket sort (dst>>8) ----------------

__global__ __launch_bounds__(256) void k_bhist(
    const int* __restrict__ ei, int* __restrict__ bktCnt)
{
    __shared__ int h[NBKT];
    int tid = threadIdx.x;
    h[tid] = 0;
    __syncthreads();
    int base = blockIdx.x*1024;
    #pragma unroll
    for (int q=0; q<4; ++q) {
        int d = ei[N_EDGES + base + q*256 + tid];
        atomicAdd(&h[d>>8], 1);
    }
    __syncthreads();
    atomicAdd(&bktCnt[tid], h[tid]);
}

__global__ __launch_bounds__(256) void k_bscan(
    const int* __restrict__ bktCnt, int* __restrict__ bktBase, int* __restrict__ bktCur)
{
    __shared__ int s[NBKT];
    int t = threadIdx.x;
    int v = bktCnt[t];
    s[t] = v;
    __syncthreads();
    for (int off=1; off<256; off<<=1) {
        int tv = (t >= off) ? s[t-off] : 0;
        __syncthreads();
        s[t] += tv;
        __syncthreads();
    }
    int ex = s[t] - v;
    bktBase[t] = ex;
    bktCur[t] = ex;
    if (t == 255) bktBase[256] = s[255];   // == N_EDGES
}

// LDS-sort 8192 edges by bucket, write packed (dst<<16|src) in coalesced runs
__global__ __launch_bounds__(256) void k_bucketA(
    const int* __restrict__ ei, int* __restrict__ bktCur, unsigned int* __restrict__ pairs)
{
    __shared__ unsigned int raw[EPB];       // 32 KB
    __shared__ unsigned int srt[EPB];       // 32 KB
    __shared__ unsigned char bOf[EPB];      // 8 KB
    __shared__ int hist[NBKT], sc[NBKT], lcur[NBKT], gbase[NBKT];
    int tid = threadIdx.x;
    hist[tid] = 0;
    __syncthreads();
    int eb = blockIdx.x * EPB;
    for (int i=tid; i<EPB; i+=256) {
        int s = ei[eb+i];
        int d = ei[N_EDGES+eb+i];
        raw[i] = ((unsigned int)d<<16) | (unsigned int)s;
        atomicAdd(&hist[d>>8], 1);
    }
    __syncthreads();
    int v = hist[tid];
    sc[tid] = v;
    __syncthreads();
    for (int off=1; off<256; off<<=1) {
        int tv = (tid >= off) ? sc[tid-off] : 0;
        __syncthreads();
        sc[tid] += tv;
        __syncthreads();
    }
    int ex = sc[tid] - v;
    sc[tid] = ex;            // exclusive local base
    lcur[tid] = ex;
    gbase[tid] = atomicAdd(&bktCur[tid], v);
    __syncthreads();
    for (int i=tid; i<EPB; i+=256) {
        unsigned int p = raw[i];
        int k = p >> 24;
        int pos = atomicAdd(&lcur[k], 1);
        srt[pos] = p;
        bOf[pos] = (unsigned char)k;
    }
    __syncthreads();
    for (int i=tid; i<EPB; i+=256) {
        int k = bOf[i];
        pairs[gbase[k] + (i - sc[k])] = srt[i];
    }
}

// per bucket: build rowptr (LDS histogram + scan) and scatter srcs into the
// bucket's contiguous CSR segment.
__global__ __launch_bounds__(256) void k_fillB(
    const int* __restrict__ bktBase, const unsigned int* __restrict__ pairs,
    int* __restrict__ rowptr, int* __restrict__ csr)
{
    __shared__ int hist[256], sc[256], cur[256];
    int b = blockIdx.x, tid = threadIdx.x;
    int node0 = b*256;
    hist[tid] = 0;
    __syncthreads();
    int s = bktBase[b], e = bktBase[b+1];
    for (int i = s + tid; i < e; i += 256)
        atomicAdd(&hist[(pairs[i] >> 16) & 255], 1);
    __syncthreads();
    int v = hist[tid];
    sc[tid] = v;
    __syncthreads();
    for (int off=1; off<256; off<<=1) {
        int tv = (tid >= off) ? sc[tid-off] : 0;
        __syncthreads();
        sc[tid] += tv;
        __syncthreads();
    }
    int base = s + sc[tid] - v;     // exclusive
    rowptr[node0 + tid] = base;
    cur[tid] = base;
    if (b == NBKT-1 && tid == 255) rowptr[N_NODES] = N_EDGES;
    __syncthreads();
    for (int i = s + tid; i < e; i += 256) {
        unsigned int p = pairs[i];
        int pos = atomicAdd(&cur[(p >> 16) & 255], 1);
        csr[pos] = (int)(p & 0xFFFFu);
    }
}

// ---------------- GIN layer kernels ----------------

// Layer-1 transform: t = x @ w1a  (fp16 out)
__global__ __launch_bounds__(256) void k_l1_transform(
    const float* __restrict__ x, const float* __restrict__ w,
    __half* __restrict__ t)
{
    __shared__ float wS[FXD*DIM];
    for (int i = threadIdx.x; i < FXD*DIM; i += 256) wS[i] = w[i];
    __syncthreads();
    int node = blockIdx.x*256 + threadIdx.x;
    float acc[DIM];
    #pragma unroll
    for (int d=0; d<DIM; ++d) acc[d] = 0.f;
    const float* xr = x + (long)node*FXD;
    for (int j=0; j<FXD; ++j) {
        float xv = xr[j];
        #pragma unroll
        for (int d=0; d<DIM; ++d) acc[d] += xv * wS[j*DIM+d];
    }
    union { __half2 h2[16]; uint4 u4[4]; } pk;
    #pragma unroll
    for (int q=0; q<16; ++q) pk.h2[q] = __floats2half2_rn(acc[2*q], acc[2*q+1]);
    uint4* dst4 = (uint4*)(t + (long)node*DIM);
    #pragma unroll
    for (int q=0; q<4; ++q) dst4[q] = pk.u4[q];
}

// Layers 2-5: h = BN(z) via scale/shift; t = h @ w  (fp16 out)
__global__ __launch_bounds__(256) void k_transform(
    const float* __restrict__ z, const float* __restrict__ ss,
    const float* __restrict__ w, __half* __restrict__ t)
{
    __shared__ float wS[DIM*DIM];
    __shared__ float sS[2*DIM];
    for (int i = threadIdx.x; i < DIM*DIM; i += 256) wS[i] = w[i];
    if (threadIdx.x < 2*DIM) sS[threadIdx.x] = ss[threadIdx.x];
    __syncthreads();
    int node = blockIdx.x*256 + threadIdx.x;
    float h[DIM];
    const float4* z4 = (const float4*)(z + (long)node*DIM);
    #pragma unroll
    for (int q=0; q<DIM/4; ++q) {
        float4 v = z4[q];
        h[q*4+0]=v.x; h[q*4+1]=v.y; h[q*4+2]=v.z; h[q*4+3]=v.w;
    }
    #pragma unroll
    for (int d=0; d<DIM; ++d) h[d] = h[d]*sS[d] + sS[DIM+d];
    float acc[DIM];
    #pragma unroll
    for (int d=0; d<DIM; ++d) acc[d] = 0.f;
    #pragma unroll
    for (int j=0; j<DIM; ++j) {
        float hv = h[j];
        #pragma unroll
        for (int d=0; d<DIM; ++d) acc[d] += hv * wS[j*DIM+d];
    }
    union { __half2 h2[16]; uint4 u4[4]; } pk;
    #pragma unroll
    for (int q=0; q<16; ++q) pk.h2[q] = __floats2half2_rn(acc[2*q], acc[2*q+1]);
    uint4* dst4 = (uint4*)(t + (long)node*DIM);
    #pragma unroll
    for (int q=0; q<4; ++q) dst4[q] = pk.u4[q];
}

// Gather (CSR) + self + MLP + ReLU + BN-stats partials.
// 4 lanes/node x 16B (uint4 = 8 halfs): one wave VMEM instr serves 16 edges.
// 64 nodes/block.
__global__ __launch_bounds__(256) void k_gather_mlp(
    const int* __restrict__ rowptr, const int* __restrict__ csr,
    const __half* __restrict__ t,
    const float* __restrict__ bi, const float* __restrict__ wo, const float* __restrict__ bo,
    float* __restrict__ z, float* __restrict__ part)
{
    __shared__ float wS[DIM*DIM];
    __shared__ float bS[2*DIM];
    __shared__ float stS[2*DIM];
    int tid = threadIdx.x;
    for (int i=tid; i<DIM*DIM; i+=256) wS[i]=wo[i];
    if (tid<DIM) bS[tid]=bi[tid];
    else if (tid<2*DIM) bS[tid]=bo[tid-DIM];
    if (tid<2*DIM) stS[tid]=0.f;
    __syncthreads();
    int g = tid >> 2;           // node 0..63 within block
    int l = tid & 3;            // lane in group; owns channels 8l..8l+7
    int node = blockIdx.x*64 + g;
    const uint4* t4 = (const uint4*)t;   // 16B = 8 halfs; 4 entries per row
    uint4 sv = t4[(long)node*4 + l];     // self term
    float a[8], c[8];
    {
        float2 q0 = __half22float2(*(const __half2*)&sv.x);
        float2 q1 = __half22float2(*(const __half2*)&sv.y);
        float2 q2 = __half22float2(*(const __half2*)&sv.z);
        float2 q3 = __half22float2(*(const __half2*)&sv.w);
        a[0]=q0.x; a[1]=q0.y; a[2]=q1.x; a[3]=q1.y;
        a[4]=q2.x; a[5]=q2.y; a[6]=q3.x; a[7]=q3.y;
    }
    #pragma unroll
    for (int q=0; q<8; ++q) c[q] = 0.f;
    int s0 = rowptr[node], s1 = rowptr[node+1];
    int e = s0;
    for (; e+8 <= s1; e+=8) {
        int my0 = csr[e + l];            // 4 consecutive dwords per group
        int my1 = csr[e + 4 + l];
        #pragma unroll
        for (int k=0; k<4; ++k) {
            int i0 = __shfl(my0, k, 4);
            uint4 v = t4[(long)i0*4 + l];
            float2 q0 = __half22float2(*(const __half2*)&v.x);
            float2 q1 = __half22float2(*(const __half2*)&v.y);
            float2 q2 = __half22float2(*(const __half2*)&v.z);
            float2 q3 = __half22float2(*(const __half2*)&v.w);
            a[0]+=q0.x; a[1]+=q0.y; a[2]+=q1.x; a[3]+=q1.y;
            a[4]+=q2.x; a[5]+=q2.y; a[6]+=q3.x; a[7]+=q3.y;
            int i1 = __shfl(my1, k, 4);
            uint4 w = t4[(long)i1*4 + l];
            float2 r0 = __half22float2(*(const __half2*)&w.x);
            float2 r1 = __half22float2(*(const __half2*)&w.y);
            float2 r2 = __half22float2(*(const __half2*)&w.z);
            float2 r3 = __half22float2(*(const __half2*)&w.w);
            c[0]+=r0.x; c[1]+=r0.y; c[2]+=r1.x; c[3]+=r1.y;
            c[4]+=r2.x; c[5]+=r2.y; c[6]+=r3.x; c[7]+=r3.y;
        }
    }
    if (e+4 <= s1) {
        int my0 = csr[e + l];
        #pragma unroll
        for (int k=0; k<4; ++k) {
            int i0 = __shfl(my0, k, 4);
            uint4 v = t4[(long)i0*4 + l];
            float2 q0 = __half22float2(*(const __half2*)&v.x);
            float2 q1 = __half22float2(*(const __half2*)&v.y);
            float2 q2 = __half22float2(*(const __half2*)&v.z);
            float2 q3 = __half22float2(*(const __half2*)&v.w);
            a[0]+=q0.x; a[1]+=q0.y; a[2]+=q1.x; a[3]+=q1.y;
            a[4]+=q2.x; a[5]+=q2.y; a[6]+=q3.x; a[7]+=q3.y;
        }
        e += 4;
    }
    for (; e<s1; ++e) {
        uint4 v = t4[(long)csr[e]*4 + l];
        float2 q0 = __half22float2(*(const __half2*)&v.x);
        float2 q1 = __half22float2(*(const __half2*)&v.y);
        float2 q2 = __half22float2(*(const __half2*)&v.z);
        float2 q3 = __half22float2(*(const __half2*)&v.w);
        a[0]+=q0.x; a[1]+=q0.y; a[2]+=q1.x; a[3]+=q1.y;
        a[4]+=q2.x; a[5]+=q2.y; a[6]+=q3.x; a[7]+=q3.y;
    }
    float ua[8];
    #pragma unroll
    for (int q=0; q<8; ++q) ua[q] = fmaxf(a[q]+c[q] + bS[8*l+q], 0.f);
    float zz[8];
    #pragma unroll
    for (int q=0; q<8; ++q) zz[q] = bS[DIM + 8*l + q];
    const float4* w4 = (const float4*)wS;
    #pragma unroll
    for (int j=0; j<DIM; ++j) {
        float uj = __shfl(ua[j & 7], j >> 3, 4);
        float4 w0 = w4[j*8 + 2*l];
        float4 w1 = w4[j*8 + 2*l + 1];
        zz[0]+=uj*w0.x; zz[1]+=uj*w0.y; zz[2]+=uj*w0.z; zz[3]+=uj*w0.w;
        zz[4]+=uj*w1.x; zz[5]+=uj*w1.y; zz[6]+=uj*w1.z; zz[7]+=uj*w1.w;
    }
    #pragma unroll
    for (int q=0; q<8; ++q) zz[q] = fmaxf(zz[q], 0.f);
    ((float4*)z)[(long)node*8 + 2*l]     = make_float4(zz[0], zz[1], zz[2], zz[3]);
    ((float4*)z)[(long)node*8 + 2*l + 1] = make_float4(zz[4], zz[5], zz[6], zz[7]);
    // stats: reduce the 16 node-groups of each wave down to 4 lanes
    float sr[8], qr[8];
    #pragma unroll
    for (int q=0; q<8; ++q) { sr[q] = zz[q]; qr[q] = zz[q]*zz[q]; }
    #pragma unroll
    for (int q=0; q<8; ++q) {
        sr[q] += __shfl_down(sr[q], 32, 64); qr[q] += __shfl_down(qr[q], 32, 64);
        sr[q] += __shfl_down(sr[q], 16, 64); qr[q] += __shfl_down(qr[q], 16, 64);
        sr[q] += __shfl_down(sr[q],  8, 64); qr[q] += __shfl_down(qr[q],  8, 64);
        sr[q] += __shfl_down(sr[q],  4, 64); qr[q] += __shfl_down(qr[q],  4, 64);
    }
    if ((tid & 63) < 4) {
        #pragma unroll
        for (int q=0; q<8; ++q) {
            atomicAdd(&stS[8*l+q],     sr[q]);
            atomicAdd(&stS[DIM+8*l+q], qr[q]);
        }
    }
    __syncthreads();
    if (tid < 2*DIM)
        atomicAdd(&part[((blockIdx.x & (NSLICE-1))<<6) + tid], stS[tid]);
}

// reduce partial stats -> scale/shift; re-zero partials for next layer
__global__ __launch_bounds__(256) void k_scaleshift(
    float* __restrict__ part,
    const float* __restrict__ gamma, const float* __restrict__ beta,
    int layer, float* __restrict__ ss)
{
    __shared__ float red[4][64];
    __shared__ float totS[64];
    int t = threadIdx.x;
    int ch = t & 63, q = t >> 6;
    float s = 0.f;
    for (int i = q*64; i < q*64 + 64; ++i) s += part[(i<<6) + ch];
    red[q][ch] = s;
    __syncthreads();
    if (t < 64) totS[t] = red[0][t]+red[1][t]+red[2][t]+red[3][t];
    __syncthreads();
    if (t < DIM) {
        float mean = totS[t] * (1.f/N_NODES);
        float var  = totS[DIM+t] * (1.f/N_NODES) - mean*mean;
        float sc = gamma[layer*DIM+t] * rsqrtf(var + 1e-5f);
        ss[t] = sc;
        ss[DIM+t] = beta[layer*DIM+t] - mean*sc;
    }
    for (int i = t; i < NSLICE*64; i += 256) part[i] = 0.f;
}

// Global add pool with BN applied: hg[batch[n]] += BN(z[n])
__global__ __launch_bounds__(256) void k_pool(
    const float* __restrict__ z, const float* __restrict__ ss,
    const int* __restrict__ batch, float* __restrict__ hg)
{
    long g = (long)blockIdx.x*256 + threadIdx.x;
    int node = (int)(g >> 5);
    int c = (int)(g & 31);
    int b = batch[node];
    float v = z[(long)node*DIM + c]*ss[c] + ss[DIM+c];
    atomicAdd(&hg[b*DIM + c], v);
}

// xd = ReLU(hg @ w_fcxd + b) -> xc[:, 0:128]
__global__ __launch_bounds__(128) void k_xd(
    const float* __restrict__ hg, const float* __restrict__ w,
    const float* __restrict__ bias, float* __restrict__ xc)
{
    int b = blockIdx.x, n = threadIdx.x;
    __shared__ float hS[DIM];
    if (n < DIM) hS[n] = hg[b*DIM+n];
    __syncthreads();
    float acc = bias[n];
    #pragma unroll
    for (int r=0; r<DIM; ++r) acc += hS[r]*w[r*OUTD+n];
    xc[b*256 + n] = fmaxf(acc, 0.f);
}

// ---------------- protein branch ----------------

// transpose conv_w (OIH) -> fp16 cwT [i][o*8+k]
__global__ __launch_bounds__(256) void k_cw_transpose(
    const float* __restrict__ cw, __half* __restrict__ cwTh)
{
    int g = blockIdx.x*256 + threadIdx.x;   // 256000 total
    int i = g >> 8;
    int j = g & 255;
    int o = j >> 3, k = j & 7;
    cwTh[g] = __float2half(cw[o*(PLEN*KS) + i*KS + k]);
}

// LDS budget <= 40 KB -> 4 blocks/CU: sort scratch and embS share one union region
__global__ __launch_bounds__(256) void k_conv(
    const int* __restrict__ target, const float* __restrict__ emb,
    const __half* __restrict__ cwTh, const float* __restrict__ conv_b,
    float* __restrict__ c)
{
    __shared__ float uni[UNIF];              // 14,072 B union region
    __shared__ float Gs[VOCAB*256];          // 26,624 B (reused as output stage)
    __shared__ float cbS[NF];
    int*   sortedS = (int*)uni;              // [0..999]
    int*   cntS    = (int*)uni + 1000;       // [26]
    int*   segS    = (int*)uni + 1026;       // [27]
    int*   curS    = (int*)uni + 1053;       // [26]
    float* embS    = uni;                    // phase 2 (after acc): skewed emb
    int b = blockIdx.x, j = threadIdx.x;
    if (j < VOCAB) cntS[j] = 0;
    if (j < NF) cbS[j] = conv_b[j];
    __syncthreads();
    int tloc[4];
    #pragma unroll
    for (int q=0; q<4; ++q) {
        int i = j + q*256;
        if (i < PLEN) {
            tloc[q] = target[b*PLEN+i];
            atomicAdd(&cntS[tloc[q]], 1);
        } else tloc[q] = -1;
    }
    __syncthreads();
    if (j == 0) {
        int run = 0;
        for (int v=0; v<VOCAB; ++v) { segS[v]=run; run += cntS[v]; }
        segS[VOCAB] = run;
    }
    __syncthreads();
    if (j < VOCAB) curS[j] = segS[j];
    __syncthreads();
    #pragma unroll
    for (int q=0; q<4; ++q) {
        int i = j + q*256;
        if (i < PLEN) {
            int pos = atomicAdd(&curS[tloc[q]], 1);
            sortedS[pos] = i;
        }
    }
    __syncthreads();
    int seg[VOCAB+1];   // keep seg in regs: uni gets overwritten by embS next
    #pragma unroll
    for (int v=0; v<=VOCAB; ++v) seg[v] = segS[v];
    // bucket-accumulate (fp16 cwT): 8-unroll, 2 independent accumulators
    for (int v=0; v<VOCAB; ++v) {
        int s = seg[v], e2 = seg[v+1];
        float accA = 0.f, accB = 0.f;
        int p = s;
        for (; p+8 <= e2; p += 8) {
            int i0=sortedS[p],   i1=sortedS[p+1], i2=sortedS[p+2], i3=sortedS[p+3];
            int i4=sortedS[p+4], i5=sortedS[p+5], i6=sortedS[p+6], i7=sortedS[p+7];
            accA += (__half2float(cwTh[i0*256+j])+__half2float(cwTh[i1*256+j]))
                  + (__half2float(cwTh[i2*256+j])+__half2float(cwTh[i3*256+j]));
            accB += (__half2float(cwTh[i4*256+j])+__half2float(cwTh[i5*256+j]))
                  + (__half2float(cwTh[i6*256+j])+__half2float(cwTh[i7*256+j]));
        }
        for (; p<e2; ++p) accA += __half2float(cwTh[sortedS[p]*256+j]);
        Gs[v*256+j] = accA + accB;
    }
    __syncthreads();
    // now safe to overwrite union with skewed emb
    for (int i=j; i<VOCAB*EMBD; i+=256) {
        int v = i >> 7, tt = i & 127;
        embS[v*EROW + tt + (tt>>4)] = emb[i];
    }
    __syncthreads();
    int o = j >> 3, pg = j & 7;
    int t0 = pg*16;
    int tcnt = (t0+16 <= CLEN) ? 16 : (CLEN - t0);   // 16 or 9
    float out[16];
    #pragma unroll
    for (int q=0; q<16; ++q) out[q] = cbS[o];
    for (int v=0; v<VOCAB; ++v) {
        float g[KS];
        #pragma unroll
        for (int k=0; k<KS; ++k) g[k] = Gs[v*256 + o*KS + k];
        float e[23];
        const float* ev = &embS[v*EROW + 17*pg];
        #pragma unroll
        for (int m=0; m<23; ++m) e[m] = ev[m + (m>>4)];
        #pragma unroll
        for (int q=0; q<16; ++q) {
            float s = 0.f;
            #pragma unroll
            for (int k=0; k<KS; ++k) s += e[q+k]*g[k];
            out[q] += s;
        }
    }
    __syncthreads();
    float* stage = Gs;
    for (int q=0; q<tcnt; ++q) stage[o*CLEN + t0 + q] = out[q];
    __syncthreads();
    for (int idx=j; idx<FCX; idx+=256)
        c[(long)b*FCX + idx] = stage[idx];
}

// xt: [1024 x 3872] @ [3872 x 128] tiled GEMM with 8-way K-split.
#define XT_KSL 484
#define XT_BK  44
__global__ __launch_bounds__(256) void k_xt(
    const float* __restrict__ c, const float* __restrict__ w,
    const float* __restrict__ bias, float* __restrict__ xc)
{
    __shared__ float cS[32][XT_BK];
    __shared__ float wS[XT_BK][128];
    int b0 = blockIdx.x * 32;
    int ks0 = blockIdx.y * XT_KSL;
    int tid = threadIdx.x;
    int cg = tid >> 5;          // graph group 0..7
    int co = tid & 31;          // col group 0..31
    float acc[4][4];
    #pragma unroll
    for (int i2=0;i2<4;++i2)
      #pragma unroll
      for (int j2=0;j2<4;++j2) acc[i2][j2]=0.f;
    for (int ch=0; ch<11; ++ch) {
        int k0 = ks0 + ch*XT_BK;
        for (int idx=tid; idx<32*XT_BK; idx+=256) {
            int g = idx / XT_BK, kk = idx - g*XT_BK;
            cS[g][kk] = c[(long)(b0+g)*FCX + k0 + kk];
        }
        for (int idx=tid; idx<XT_BK*128; idx+=256) {
            int kk = idx >> 7, n = idx & 127;
            wS[kk][n] = w[(long)(k0+kk)*OUTD + n];
        }
        __syncthreads();
        #pragma unroll 4
        for (int kk=0; kk<XT_BK; ++kk) {
            float cv[4], wv[4];
            #pragma unroll
            for (int q=0;q<4;++q) cv[q] = cS[cg*4+q][kk];
            #pragma unroll
            for (int p=0;p<4;++p) wv[p] = wS[kk][co*4+p];
            #pragma unroll
            for (int q=0;q<4;++q)
              #pragma unroll
              for (int p=0;p<4;++p) acc[q][p] += cv[q]*wv[p];
        }
        __syncthreads();
    }
    #pragma unroll
    for (int q=0;q<4;++q) {
        int g = b0 + cg*4 + q;
        #pragma unroll
        for (int p=0;p<4;++p) {
            int n = co*4 + p;
            float v = acc[q][p];
            if (blockIdx.y == 0) v += bias[n];
            atomicAdd(&xc[g*256 + 128 + n], v);
        }
    }
}

// ---------------- joint head ----------------

__global__ __launch_bounds__(256) void k_fc1(
    const float* __restrict__ xc, const float* __restrict__ w,
    const float* __restrict__ bias, float* __restrict__ y)
{
    __shared__ float xS[4][256];
    int b0 = blockIdx.x*4, n = threadIdx.x;
    #pragma unroll
    for (int q=0; q<4; ++q) xS[q][n] = xc[(b0+q)*256 + n];
    __syncthreads();
    float acc[4][4];
    #pragma unroll
    for (int m=0; m<4; ++m) {
        float bv = bias[m*256+n];
        #pragma unroll
        for (int q=0; q<4; ++q) acc[q][m] = bv;
    }
    for (int r=0; r<256; ++r) {
        float x0=xS[0][r], x1=xS[1][r], x2=xS[2][r], x3=xS[3][r];
        #pragma unroll
        for (int m=0; m<4; ++m) {
            float wv = w[r*1024 + m*256 + n];
            acc[0][m]+=x0*wv; acc[1][m]+=x1*wv; acc[2][m]+=x2*wv; acc[3][m]+=x3*wv;
        }
    }
    #pragma unroll
    for (int q=0; q<4; ++q)
        #pragma unroll
        for (int m=0; m<4; ++m)
            y[(b0+q)*1024 + m*256 + n] = fmaxf(acc[q][m], 0.f);
}

__global__ __launch_bounds__(256) void k_fc2(
    const float* __restrict__ y, const float* __restrict__ w,
    const float* __restrict__ bias, float* __restrict__ y2)
{
    __shared__ float xS[4][1024];
    int b0 = blockIdx.x*4, n = threadIdx.x;
    #pragma unroll
    for (int q=0; q<4; ++q)
        for (int i=n; i<1024; i+=256) xS[q][i] = y[(b0+q)*1024 + i];
    __syncthreads();
    float acc[4];
    #pragma unroll
    for (int q=0; q<4; ++q) acc[q] = bias[n];
    for (int r=0; r<1024; ++r) {
        float wv = w[r*256 + n];
        #pragma unroll
        for (int q=0; q<4; ++q) acc[q] += xS[q][r]*wv;
    }
    #pragma unroll
    for (int q=0; q<4; ++q) y2[(b0+q)*256 + n] = fmaxf(acc[q], 0.f);
}

__global__ __launch_bounds__(256) void k_out(
    const float* __restrict__ y2, const float* __restrict__ w,
    const float* __restrict__ bias, float* __restrict__ out)
{
    int b = blockIdx.x, n = threadIdx.x;
    float v = y2[b*256 + n] * w[n];
    #pragma unroll
    for (int off=32; off; off>>=1) v += __shfl_down(v, off, 64);
    __shared__ float red[4];
    if ((n & 63) == 0) red[n >> 6] = v;
    __syncthreads();
    if (n == 0) out[b] = red[0]+red[1]+red[2]+red[3] + bias[0];
}

// ---------------- launch ----------------

extern "C" void kernel_launch(void* const* d_in, const int* in_sizes, int n_in,
                              void* d_out, int out_size, void* d_ws, size_t ws_size,
                              hipStream_t stream) {
    const float* x      = (const float*)d_in[0];
    const int*   ei     = (const int*)  d_in[1];
    const int*   batch  = (const int*)  d_in[2];
    const int*   target = (const int*)  d_in[3];
    const float* w1a    = (const float*)d_in[4];
    const float* b1a    = (const float*)d_in[5];
    const float* w1b    = (const float*)d_in[6];
    const float* b1b    = (const float*)d_in[7];
    const float* wa     = (const float*)d_in[8];
    const float* ba     = (const float*)d_in[9];
    const float* wb     = (const float*)d_in[10];
    const float* bb     = (const float*)d_in[11];
    const float* gamma  = (const float*)d_in[12];
    const float* beta   = (const float*)d_in[13];
    const float* w_fcxd = (const float*)d_in[14];
    const float* b_fcxd = (const float*)d_in[15];
    const float* emb    = (const float*)d_in[16];
    const float* conv_w = (const float*)d_in[17];
    const float* conv_b = (const float*)d_in[18];
    const float* w_fcxt = (const float*)d_in[19];
    const float* b_fcxt = (const float*)d_in[20];
    const float* w_fc1  = (const float*)d_in[21];
    const float* b_fc1  = (const float*)d_in[22];
    const float* w_fc2  = (const float*)d_in[23];
    const float* b_fc2  = (const float*)d_in[24];
    const float* w_out  = (const float*)d_in[25];
    const float* b_out  = (const float*)d_in[26];

    float* ws      = (float*)d_ws;
    __half* tH     = (__half*)ws;                          // N*32 halfs = 1,048,576 float-slots
    float* z       = ws + 1048576;                         // N*32 floats
    unsigned int* pairs = (unsigned int*)(z + (size_t)N_NODES*DIM);  // E uints
    int*   csr     = (int*)(pairs + N_EDGES);              // E ints
    int*   rowptr  = csr + N_EDGES;                        // N+1 (+pad)
    int*   bktCnt  = rowptr + (N_NODES + 8);               // 256
    int*   bktBase = bktCnt + 256;                         // 257 (+pad)
    int*   bktCur  = bktBase + 264;                        // 256
    float* ss      = (float*)(bktCur + 256);               // 64
    float* hg      = ss + 64;                              // 32768
    __half* cwTh   = (__half*)(hg + (size_t)NB*DIM);       // 256000 halfs = 128000 slots
    float* cbuf    = hg + (size_t)NB*DIM + 128000;         // NB*FCX
    float* xc      = cbuf + (size_t)NB*FCX;                // 262144
    float* y1      = xc + (size_t)NB*256;                  // 1048576
    float* y2      = y1 + (size_t)NB*1024;                 // 262144
    float* part    = y2 + (size_t)NB*256;                  // 256*64

    // ---- CSR build: bucket sort (coalesced) + fused rowptr/scatter ----
    hipMemsetAsync(bktCnt, 0, 256*sizeof(int), stream);
    k_bhist<<<N_EDGES/1024, 256, 0, stream>>>(ei, bktCnt);
    k_bscan<<<1, 256, 0, stream>>>(bktCnt, bktBase, bktCur);
    k_bucketA<<<NBKT, 256, 0, stream>>>(ei, bktCur, pairs);
    k_fillB<<<NBKT, 256, 0, stream>>>(bktBase, pairs, rowptr, csr);

    // ---- protein branch ----
    hipMemsetAsync(xc, 0, (size_t)NB*256*sizeof(float), stream);
    k_cw_transpose<<<1000, 256, 0, stream>>>(conv_w, cwTh);
    k_conv<<<NB, 256, 0, stream>>>(target, emb, cwTh, conv_b, cbuf);
    k_xt<<<dim3(32, 8), 256, 0, stream>>>(cbuf, w_fcxt, b_fcxt, xc);

    // ---- GIN layers ----
    hipMemsetAsync(part, 0, NSLICE*64*sizeof(float), stream);
    for (int l=0; l<5; ++l) {
        if (l == 0)
            k_l1_transform<<<N_NODES/256, 256, 0, stream>>>(x, w1a, tH);
        else
            k_transform<<<N_NODES/256, 256, 0, stream>>>(z, ss, wa + (size_t)(l-1)*DIM*DIM, tH);
        const float* bi = (l==0) ? b1a : ba + (size_t)(l-1)*DIM;
        const float* wo = (l==0) ? w1b : wb + (size_t)(l-1)*DIM*DIM;
        const float* bo = (l==0) ? b1b : bb + (size_t)(l-1)*DIM;
        k_gather_mlp<<<N_NODES/64, 256, 0, stream>>>(rowptr, csr, tH, bi, wo, bo, z, part);
        k_scaleshift<<<1, 256, 0, stream>>>(part, gamma, beta, l, ss);
    }

    // ---- pool + drug head ----
    hipMemsetAsync(hg, 0, (size_t)NB*DIM*sizeof(float), stream);
    k_pool<<<(N_NODES*32)/256, 256, 0, stream>>>(z, ss, batch, hg);
    k_xd<<<NB, 128, 0, stream>>>(hg, w_fcxd, b_fcxd, xc);

    // ---- joint head ----
    k_fc1<<<NB/4, 256, 0, stream>>>(xc, w_fc1, b_fc1, y1);
    k_fc2<<<NB/4, 256, 0, stream>>>(y1, w_fc2, b_fc2, y2);
    k_out<<<NB, 256, 0, stream>>>(y2, w_out, b_out, (float*)d_out);
}